// Round 1
// baseline (74.065 us; speedup 1.0000x reference)
//
#include <hip/hip_runtime.h>

#define B_N 8
#define C_N 8
#define F_N 257
#define T_N 2000
#define EPSF 1e-6f

// One block per batch. Phase A: mean over F of |X[b, rc, f, t]| -> LDS.
// Phase B: parallel affine scan of mu_t = a_t*mu_{t-1} + (1-a_t)*x_t,
// write inv[b][t] = 1/(mu_t + eps) to workspace.
__global__ __launch_bounds__(512) void mean_scan_kernel(
    const float* __restrict__ X, const int* __restrict__ ref_ch,
    float4* __restrict__ inv4 /* [B][T/4] */)
{
    __shared__ float s_mean[T_N];
    __shared__ float s_wA[8];
    __shared__ float s_wB[8];
    const float ALPHA = (float)(191.0 / 193.0);

    const int b   = blockIdx.x;
    const int tid = threadIdx.x;
    const int rc  = ref_ch[0];

    const float4* Xb4 =
        (const float4*)(X + ((size_t)(b * C_N + rc)) * (size_t)F_N * T_N);

    // ---- Phase A: mean over F (float4 columns, coalesced) ----
    if (tid < T_N / 4) {
        float ax = 0.f, ay = 0.f, az = 0.f, aw = 0.f;
        for (int f = 0; f < F_N; ++f) {
            float4 v = Xb4[f * (T_N / 4) + tid];
            ax += fabsf(v.x); ay += fabsf(v.y);
            az += fabsf(v.z); aw += fabsf(v.w);
        }
        const int t = tid * 4;
        s_mean[t + 0] = ax / (float)F_N;
        s_mean[t + 1] = ay / (float)F_N;
        s_mean[t + 2] = az / (float)F_N;
        s_mean[t + 3] = aw / (float)F_N;
    }
    __syncthreads();

    // ---- Phase B: affine scan. Transform (A,B): mu -> A*mu + B ----
    // Local composite over this thread's 4 consecutive t's.
    float A = 1.f, Bv = 0.f;
    const int tbase = tid * 4;
    #pragma unroll
    for (int k = 0; k < 4; ++k) {
        const int t = tbase + k;
        if (t < T_N) {
            const float tf = (float)t;
            const float a = fminf((tf - 1.f) / (tf + 1.f), ALPHA);
            const float x = s_mean[t];
            Bv = a * Bv + (1.f - a) * x;   // compose after existing
            A  = a * A;
        }
    }

    // Inclusive Hillis-Steele scan across the 64-lane wave.
    const int lane = tid & 63;
    #pragma unroll
    for (int d = 1; d < 64; d <<= 1) {
        const float pA = __shfl_up(A, d);
        const float pB = __shfl_up(Bv, d);
        if (lane >= d) {
            Bv = A * pB + Bv;   // (mine) ∘ (prev)
            A  = A * pA;
        }
    }

    // Cross-wave scan (8 waves) via LDS; thread 0 converts to exclusive.
    const int wid = tid >> 6;
    if (lane == 63) { s_wA[wid] = A; s_wB[wid] = Bv; }
    __syncthreads();
    if (tid == 0) {
        float cA = 1.f, cB = 0.f;
        #pragma unroll
        for (int w = 0; w < 8; ++w) {
            const float nA = s_wA[w] * cA;
            const float nB = s_wA[w] * cB + s_wB[w];
            s_wA[w] = cA; s_wB[w] = cB;   // store exclusive prefix
            cA = nA; cB = nB;
        }
    }
    __syncthreads();

    // Exclusive prefix for this thread = (lane-1 inclusive) ∘ (wave prefix).
    float eA = __shfl_up(A, 1);
    float eB = __shfl_up(Bv, 1);
    if (lane == 0) { eA = 1.f; eB = 0.f; }
    const float wB = s_wB[wid];
    float mu = eA * wB + eB;   // applied to mu0 = 0 => just the B component

    // Replay the 4 local elements, write reciprocals.
    if (tid < T_N / 4) {
        float r[4];
        #pragma unroll
        for (int k = 0; k < 4; ++k) {
            const int t = tbase + k;
            const float tf = (float)t;
            const float a = fminf((tf - 1.f) / (tf + 1.f), ALPHA);
            const float x = s_mean[t];
            mu = a * mu + (1.f - a) * x;
            r[k] = 1.f / (mu + EPSF);
        }
        inv4[b * (T_N / 4) + tid] = make_float4(r[0], r[1], r[2], r[3]);
    }
}

// Pure streaming: out[b,c,f,t] = X[b,c,f,t] * inv[b,t]
__global__ __launch_bounds__(256) void norm_kernel(
    const float4* __restrict__ X4,
    const float4* __restrict__ inv4,
    float4* __restrict__ out4)
{
    const int N4    = B_N * C_N * F_N * T_N / 4;   // 8,224,000
    const int PER_B = C_N * F_N * T_N / 4;         // 1,028,000
    const int idx = blockIdx.x * 256 + threadIdx.x;
    if (idx >= N4) return;

    const int b  = idx / PER_B;
    const int tq = idx % (T_N / 4);

    const float4 iv = inv4[b * (T_N / 4) + tq];
    const float4 x  = X4[idx];
    out4[idx] = make_float4(x.x * iv.x, x.y * iv.y, x.z * iv.z, x.w * iv.w);
}

extern "C" void kernel_launch(void* const* d_in, const int* in_sizes, int n_in,
                              void* d_out, int out_size, void* d_ws, size_t ws_size,
                              hipStream_t stream) {
    const float* X  = (const float*)d_in[0];
    const int*   rc = (const int*)d_in[1];
    float* inv = (float*)d_ws;   // B_N * T_N floats = 64 KB

    mean_scan_kernel<<<B_N, 512, 0, stream>>>(X, rc, (float4*)inv);

    const int N4 = B_N * C_N * F_N * T_N / 4;
    norm_kernel<<<(N4 + 255) / 256, 256, 0, stream>>>(
        (const float4*)X, (const float4*)inv, (float4*)d_out);
}

// Round 2
// 55.514 us; speedup vs baseline: 1.3342x; 1.3342x over previous
//
#include <hip/hip_runtime.h>

#define B_N 8
#define C_N 8
#define F_N 257
#define T_N 2000
#define EPSF 1e-6f

#define FCH 16            // F chunks
#define FPC 17            // ceil(257/16) rows per chunk

// ---- Kernel A: partial |X[b,rc,f,t]| sums over an F-chunk. Wide grid. ----
__global__ __launch_bounds__(512) void partial_mean_kernel(
    const float* __restrict__ X, const int* __restrict__ ref_ch,
    float4* __restrict__ part4 /* [B][FCH][T/4] */)
{
    const int b   = blockIdx.x;
    const int c   = blockIdx.y;
    const int tid = threadIdx.x;
    if (tid >= T_N / 4) return;

    const int rc = ref_ch[0];
    const float4* Xb4 =
        (const float4*)(X + ((size_t)(b * C_N + rc)) * (size_t)F_N * T_N);

    const int f0 = c * FPC;
    const int f1 = (f0 + FPC < F_N) ? (f0 + FPC) : F_N;

    float ax = 0.f, ay = 0.f, az = 0.f, aw = 0.f;
    for (int f = f0; f < f1; ++f) {
        float4 v = Xb4[f * (T_N / 4) + tid];
        ax += fabsf(v.x); ay += fabsf(v.y);
        az += fabsf(v.z); aw += fabsf(v.w);
    }
    part4[(b * FCH + c) * (T_N / 4) + tid] = make_float4(ax, ay, az, aw);
}

// ---- Kernel B: reduce partials -> mean, then parallel affine scan ->
//      inv[b][t] = 1/(mu_t + eps). One block per batch (tiny). ----
__global__ __launch_bounds__(512) void scan_kernel(
    const float4* __restrict__ part4,
    float4* __restrict__ inv4 /* [B][T/4] */)
{
    __shared__ float s_mean[T_N];
    __shared__ float s_wA[8];
    __shared__ float s_wB[8];
    const float ALPHA = (float)(191.0 / 193.0);

    const int b   = blockIdx.x;
    const int tid = threadIdx.x;

    if (tid < T_N / 4) {
        float ax = 0.f, ay = 0.f, az = 0.f, aw = 0.f;
        #pragma unroll
        for (int c = 0; c < FCH; ++c) {
            float4 v = part4[(b * FCH + c) * (T_N / 4) + tid];
            ax += v.x; ay += v.y; az += v.z; aw += v.w;
        }
        const int t = tid * 4;
        const float inv_f = 1.f / (float)F_N;
        s_mean[t + 0] = ax * inv_f;
        s_mean[t + 1] = ay * inv_f;
        s_mean[t + 2] = az * inv_f;
        s_mean[t + 3] = aw * inv_f;
    }
    __syncthreads();

    // Affine scan: transform (A,B): mu -> A*mu + B. Local composite of 4 t's.
    float A = 1.f, Bv = 0.f;
    const int tbase = tid * 4;
    #pragma unroll
    for (int k = 0; k < 4; ++k) {
        const int t = tbase + k;
        if (t < T_N) {
            const float tf = (float)t;
            const float a = fminf((tf - 1.f) / (tf + 1.f), ALPHA);
            const float x = s_mean[t];
            Bv = a * Bv + (1.f - a) * x;
            A  = a * A;
        }
    }

    // Inclusive Hillis-Steele scan across the 64-lane wave.
    const int lane = tid & 63;
    #pragma unroll
    for (int d = 1; d < 64; d <<= 1) {
        const float pA = __shfl_up(A, d);
        const float pB = __shfl_up(Bv, d);
        if (lane >= d) {
            Bv = A * pB + Bv;
            A  = A * pA;
        }
    }

    // Cross-wave (8 waves) exclusive composite via LDS.
    const int wid = tid >> 6;
    if (lane == 63) { s_wA[wid] = A; s_wB[wid] = Bv; }
    __syncthreads();
    if (tid == 0) {
        float cA = 1.f, cB = 0.f;
        #pragma unroll
        for (int w = 0; w < 8; ++w) {
            const float nA = s_wA[w] * cA;
            const float nB = s_wA[w] * cB + s_wB[w];
            s_wA[w] = cA; s_wB[w] = cB;
            cA = nA; cB = nB;
        }
    }
    __syncthreads();

    float eA = __shfl_up(A, 1);
    float eB = __shfl_up(Bv, 1);
    if (lane == 0) { eA = 1.f; eB = 0.f; }
    float mu = eA * s_wB[wid] + eB;   // applied to mu0 = 0

    if (tid < T_N / 4) {
        float r[4];
        #pragma unroll
        for (int k = 0; k < 4; ++k) {
            const int t = tbase + k;
            const float tf = (float)t;
            const float a = fminf((tf - 1.f) / (tf + 1.f), ALPHA);
            const float x = s_mean[t];
            mu = a * mu + (1.f - a) * x;
            r[k] = 1.f / (mu + EPSF);
        }
        inv4[b * (T_N / 4) + tid] = make_float4(r[0], r[1], r[2], r[3]);
    }
}

// ---- Kernel C: pure streaming out[b,c,f,t] = X[b,c,f,t] * inv[b,t] ----
__global__ __launch_bounds__(256) void norm_kernel(
    const float4* __restrict__ X4,
    const float4* __restrict__ inv4,
    float4* __restrict__ out4)
{
    const int N4    = B_N * C_N * F_N * T_N / 4;   // 8,224,000
    const int PER_B = C_N * F_N * T_N / 4;         // 1,028,000
    const int idx = blockIdx.x * 256 + threadIdx.x;
    if (idx >= N4) return;

    const int b  = idx / PER_B;
    const int tq = idx % (T_N / 4);

    const float4 iv = inv4[b * (T_N / 4) + tq];
    const float4 x  = X4[idx];
    out4[idx] = make_float4(x.x * iv.x, x.y * iv.y, x.z * iv.z, x.w * iv.w);
}

extern "C" void kernel_launch(void* const* d_in, const int* in_sizes, int n_in,
                              void* d_out, int out_size, void* d_ws, size_t ws_size,
                              hipStream_t stream) {
    const float* X  = (const float*)d_in[0];
    const int*   rc = (const int*)d_in[1];

    float* inv  = (float*)d_ws;                    // B*T floats   = 64 KB
    float* part = (float*)d_ws + B_N * T_N;        // B*FCH*T      = 1 MB

    dim3 gA(B_N, FCH);
    partial_mean_kernel<<<gA, 512, 0, stream>>>(X, rc, (float4*)part);

    scan_kernel<<<B_N, 512, 0, stream>>>((const float4*)part, (float4*)inv);

    const int N4 = B_N * C_N * F_N * T_N / 4;
    norm_kernel<<<(N4 + 255) / 256, 256, 0, stream>>>(
        (const float4*)X, (const float4*)inv, (float4*)d_out);
}